// Round 1
// baseline (1770.525 us; speedup 1.0000x reference)
//
#include <hip/hip_runtime.h>
#include <hip/hip_bf16.h>
#include <math.h>

#define NNODES 50000
#define NEDGES 800000
#define RDIM   300
#define KPAD   320            // K padded to multiple of 32 for MFMA
#define LDA    328            // LDS row stride (bf16 elems) for rbf tile: 656 B, 16B-aligned
#define LDW    72             // LDS row stride for w1 tile: 144 B, 16B-aligned
#define MSG_LD 66             // LDS row stride (f32) for msg tile (aliases rbf tile)

typedef __attribute__((ext_vector_type(8))) short short8;
typedef __attribute__((ext_vector_type(4))) float floatx4;

__device__ __forceinline__ float ssp(float x) {
    // softplus(x) - ln2, numerically stable
    return fmaxf(x, 0.0f) + log1pf(expf(-fabsf(x))) - 0.69314718056f;
}

__device__ __forceinline__ unsigned short f2bf(float f) {
    unsigned int u = __float_as_uint(f);
    unsigned int r = (u + 0x7FFFu + ((u >> 16) & 1u)) >> 16;   // RNE
    return (unsigned short)r;
}

// ---------------- prep: transpose weights to bf16 [n][k] layouts ----------------
__global__ void prep_weights(const float* __restrict__ fw1, const float* __restrict__ fw2,
                             unsigned short* __restrict__ fw1t, unsigned short* __restrict__ fw2t) {
    int t = threadIdx.x + blockIdx.x * blockDim.x;
    int stride = blockDim.x * gridDim.x;
    for (int idx = t; idx < 64 * KPAD; idx += stride) {
        int n = idx / KPAD, k = idx - n * KPAD;
        float v = (k < RDIM) ? fw1[k * 64 + n] : 0.0f;
        fw1t[idx] = f2bf(v);
    }
    for (int idx = t; idx < 64 * 64; idx += stride) {
        int n = idx >> 6, k = idx & 63;
        fw2t[idx] = f2bf(fw2[k * 64 + n]);
    }
}

// ---------------- h = x @ l1w + l1b ----------------
__global__ __launch_bounds__(256) void linear1_kernel(const float* __restrict__ x,
    const float* __restrict__ w, const float* __restrict__ b, float* __restrict__ h) {
    __shared__ float xs[64][65];
    __shared__ float ws[64][65];
    int t = threadIdx.x;
    int r0 = blockIdx.x * 64;
    for (int i = t; i < 4096; i += 256) ws[i >> 6][i & 63] = w[i];
    for (int i = t; i < 4096; i += 256) {
        int r = i >> 6;
        xs[r][i & 63] = (r0 + r < NNODES) ? x[(size_t)(r0 + r) * 64 + (i & 63)] : 0.0f;
    }
    __syncthreads();
    int c = t & 63;
    int rb = t >> 6;
    float bias = b[c];
    #pragma unroll 4
    for (int ri = 0; ri < 16; ri++) {
        int r = rb * 16 + ri;
        float acc = bias;
        #pragma unroll
        for (int k = 0; k < 64; k++) acc += xs[r][k] * ws[k][c];
        if (r0 + r < NNODES) h[(size_t)(r0 + r) * 64 + c] = acc;
    }
}

// ---------------- counting sort by dst: hist -> scan -> scatter perm ----------------
__global__ __launch_bounds__(256) void hist_kernel(const int* __restrict__ ei,
                                                   int* __restrict__ deg) {
    int e = threadIdx.x + blockIdx.x * 256;
    if (e < NEDGES) atomicAdd(&deg[ei[e]], 1);
}

__global__ __launch_bounds__(1024) void scan_kernel(const int* __restrict__ deg,
                                                    int* __restrict__ cursor) {
    __shared__ int buf[1024];
    __shared__ int base_s;
    int t = threadIdx.x;
    if (t == 0) base_s = 0;
    __syncthreads();
    for (int tile = 0; tile < NNODES; tile += 1024) {
        int idx = tile + t;
        int v = (idx < NNODES) ? deg[idx] : 0;
        buf[t] = v;
        __syncthreads();
        for (int off = 1; off < 1024; off <<= 1) {
            int self = buf[t];
            int x = (t >= off) ? buf[t - off] : 0;
            __syncthreads();
            buf[t] = self + x;
            __syncthreads();
        }
        if (idx < NNODES) cursor[idx] = base_s + buf[t] - v;   // exclusive
        __syncthreads();
        if (t == 0) base_s += buf[1023];
        __syncthreads();
    }
}

__global__ __launch_bounds__(256) void scatter_kernel(const int* __restrict__ ei,
                                                      int* __restrict__ cursor,
                                                      int* __restrict__ perm) {
    int e = threadIdx.x + blockIdx.x * 256;
    if (e < NEDGES) {
        int slot = atomicAdd(&cursor[ei[e]], 1);
        perm[slot] = e;
    }
}

// ---------------- edge kernel: filter-gen GEMMs + cutoff + gather, dst-sorted,
//                  LDS segmented reduce -> few atomics ----------------
__global__ __launch_bounds__(256) void edge_kernel(
    const int* __restrict__ ei,                // [2][E] int32
    const int* __restrict__ perm,              // [E] edge ids sorted by dst
    const float* __restrict__ rbf,             // [E][300]
    const float* __restrict__ dist,            // [E]
    const float* __restrict__ cutoffp,         // [1]
    const unsigned short* __restrict__ fw1t,   // [64][320] bf16
    const float* __restrict__ fb1,             // [64]
    const unsigned short* __restrict__ fw2t,   // [64][64] bf16
    const float* __restrict__ fb2,             // [64]
    const float* __restrict__ h,               // [N][64]
    float* __restrict__ agg)                   // [N][64] (d_out, zeroed)
{
    __shared__ __align__(16) unsigned short rbf_s[64 * LDA];
    __shared__ __align__(16) unsigned short w1_s[64 * LDW];
    __shared__ float cut_s[64];
    __shared__ int src_s[64], dst_s[64], ep_s[64];

    // msg tile aliases the rbf tile: rbf_s is dead after GEMM1, and all GEMM1
    // reads complete before the pre-GEMM2 __syncthreads().
    float (*msg_s)[MSG_LD] = (float (*)[MSG_LD])rbf_s;   // 64*66*4 = 16896 B <= 41984 B

    const int t = threadIdx.x;
    const int e0 = blockIdx.x * 64;
    const int lane = t & 63;
    const int wv = t >> 6;                 // wave 0..3: owns n-cols [16*wv, 16*wv+16)

    // edge metadata (dst-sorted order)
    if (t < 64) {
        int e = perm[e0 + t];
        ep_s[t] = e;
        dst_s[t] = ei[e];                  // non-decreasing across the tile
        src_s[t] = ei[NEDGES + e];
        float co = *cutoffp;
        cut_s[t] = 1.0f + cosf(3.14159265f * dist[e] / co);
    }

    // register-resident B fragments (per wave's n-tile) + biases
    const int n = (wv << 4) + (lane & 15);
    const int kb = (lane >> 4) << 3;
    short8 b1[10];
    #pragma unroll
    for (int ks = 0; ks < 10; ks++)
        b1[ks] = *(const short8*)&fw1t[n * KPAD + ks * 32 + kb];
    short8 b2[2];
    #pragma unroll
    for (int ks = 0; ks < 2; ks++)
        b2[ks] = *(const short8*)&fw2t[n * 64 + ks * 32 + kb];
    const float fb1n = fb1[n];
    const float fb2n = fb2[n];

    __syncthreads();   // ep_s ready for the gathered staging

    // stage rbf rows (gathered via perm) -> LDS bf16. 64 rows x 75 float4 each.
    {
        #pragma unroll
        for (int i = 0; i < 19; i++) {
            int idx4 = t + 256 * i;
            if (idx4 < 4800) {
                int row = idx4 / 75;          // 75 float4 per row (300 floats)
                int col4 = idx4 - row * 75;
                const float4* rowp = (const float4*)(rbf + (size_t)ep_s[row] * RDIM);
                float4 v = rowp[col4];
                unsigned long long packed =
                    (unsigned long long)f2bf(v.x)
                  | ((unsigned long long)f2bf(v.y) << 16)
                  | ((unsigned long long)f2bf(v.z) << 32)
                  | ((unsigned long long)f2bf(v.w) << 48);
                *(unsigned long long*)&rbf_s[row * LDA + col4 * 4] = packed;
            }
        }
        if (t < 64) {  // zero-pad k = 300..319
            #pragma unroll
            for (int c4 = 75; c4 < 80; c4++)
                *(unsigned long long*)&rbf_s[t * LDA + c4 * 4] = 0ULL;
        }
    }
    __syncthreads();

    // GEMM1: W1[64 edges][16 n] per wave = ssp(rbf @ fw1 + fb1)
    const floatx4 zero4 = {0.0f, 0.0f, 0.0f, 0.0f};
    floatx4 acc[4] = {zero4, zero4, zero4, zero4};
    const int arow = lane & 15;
    #pragma unroll
    for (int ks = 0; ks < 10; ks++) {
        #pragma unroll
        for (int mt = 0; mt < 4; mt++) {
            short8 a = *(const short8*)&rbf_s[(mt * 16 + arow) * LDA + ks * 32 + kb];
            acc[mt] = __builtin_amdgcn_mfma_f32_16x16x32_bf16(a, b1[ks], acc[mt], 0, 0, 0);
        }
    }

    // bias + ssp, write W1 to LDS in bf16 (A-layout source for GEMM2)
    #pragma unroll
    for (int mt = 0; mt < 4; mt++) {
        #pragma unroll
        for (int r = 0; r < 4; r++) {
            int edge = mt * 16 + ((lane >> 4) << 2) + r;
            float v = ssp(acc[mt][r] + fb1n);
            w1_s[edge * LDW + n] = f2bf(v);
        }
    }
    __syncthreads();   // w1_s ready; all rbf_s reads complete -> msg_s alias safe

    // GEMM2: W2 = ssp(W1 @ fw2 + fb2)
    floatx4 acc2[4] = {zero4, zero4, zero4, zero4};
    #pragma unroll
    for (int ks = 0; ks < 2; ks++) {
        #pragma unroll
        for (int mt = 0; mt < 4; mt++) {
            short8 a = *(const short8*)&w1_s[(mt * 16 + arow) * LDW + ks * 32 + kb];
            acc2[mt] = __builtin_amdgcn_mfma_f32_16x16x32_bf16(a, b2[ks], acc2[mt], 0, 0, 0);
        }
    }

    // epilogue: cutoff * ssp(.) ; msg = w * h[src] -> LDS msg tile
    #pragma unroll
    for (int mt = 0; mt < 4; mt++) {
        #pragma unroll
        for (int r = 0; r < 4; r++) {
            int el = mt * 16 + ((lane >> 4) << 2) + r;
            float w2v = ssp(acc2[mt][r] + fb2n) * cut_s[el];
            msg_s[el][n] = w2v * h[(size_t)src_s[el] * 64 + n];
        }
    }
    __syncthreads();

    // segmented reduce over dst-sorted rows: wave wv walks rows [16wv,16wv+16),
    // lane = feature column. dst_s is wave-uniform -> no divergence.
    // Flushes per column ~= (#distinct dst in tile) + 3 chunk splits (~7 avg)
    // instead of 64 -> ~9x fewer device-scope atomics.
    {
        const int c = lane;
        const int r0 = wv * 16;
        int cur = dst_s[r0];
        float acc3 = 0.0f;
        #pragma unroll
        for (int r = r0; r < r0 + 16; ++r) {
            int d = dst_s[r];
            if (d != cur) {
                atomicAdd(&agg[(size_t)cur * 64 + c], acc3);
                acc3 = 0.0f;
                cur = d;
            }
            acc3 += msg_s[r][c];
        }
        atomicAdd(&agg[(size_t)cur * 64 + c], acc3);
    }
}

// ---------------- out = ssp(agg@l2w+l2b)@l3w + l3b + x0, in-place on d_out ----------------
__global__ __launch_bounds__(256) void output_kernel(float* __restrict__ out,
    const float* __restrict__ x0,
    const float* __restrict__ l2w, const float* __restrict__ l2b,
    const float* __restrict__ l3w, const float* __restrict__ l3b) {
    __shared__ float as[64][65];
    __shared__ float w2s[64][65];
    __shared__ float w3s[64][65];
    __shared__ float ts[64][65];
    int t = threadIdx.x;
    int r0 = blockIdx.x * 64;
    for (int i = t; i < 4096; i += 256) w2s[i >> 6][i & 63] = l2w[i];
    for (int i = t; i < 4096; i += 256) w3s[i >> 6][i & 63] = l3w[i];
    for (int i = t; i < 4096; i += 256) {
        int r = i >> 6;
        as[r][i & 63] = (r0 + r < NNODES) ? out[(size_t)(r0 + r) * 64 + (i & 63)] : 0.0f;
    }
    __syncthreads();
    int c = t & 63;
    int rb = t >> 6;
    float b2 = l2b[c];
    #pragma unroll 4
    for (int ri = 0; ri < 16; ri++) {
        int r = rb * 16 + ri;
        float acc = b2;
        #pragma unroll
        for (int k = 0; k < 64; k++) acc += as[r][k] * w2s[k][c];
        ts[r][c] = ssp(acc);
    }
    __syncthreads();
    float b3 = l3b[c];
    #pragma unroll 4
    for (int ri = 0; ri < 16; ri++) {
        int r = rb * 16 + ri;
        float acc = b3;
        #pragma unroll
        for (int k = 0; k < 64; k++) acc += ts[r][k] * w3s[k][c];
        if (r0 + r < NNODES)
            out[(size_t)(r0 + r) * 64 + c] = acc + x0[(size_t)(r0 + r) * 64 + c];
    }
}

extern "C" void kernel_launch(void* const* d_in, const int* in_sizes, int n_in,
                              void* d_out, int out_size, void* d_ws, size_t ws_size,
                              hipStream_t stream) {
    const int* ei              = (const int*)d_in[0];     // int inputs arrive as int32
    const float* node_feature  = (const float*)d_in[1];
    const float* rbf           = (const float*)d_in[2];
    const float* dist          = (const float*)d_in[3];
    const float* cutoff        = (const float*)d_in[4];
    const float* fw1           = (const float*)d_in[5];
    const float* fb1           = (const float*)d_in[6];
    const float* fw2           = (const float*)d_in[7];
    const float* fb2           = (const float*)d_in[8];
    const float* l1w           = (const float*)d_in[9];
    const float* l1b           = (const float*)d_in[10];
    const float* l2w           = (const float*)d_in[11];
    const float* l2b           = (const float*)d_in[12];
    const float* l3w           = (const float*)d_in[13];
    const float* l3b           = (const float*)d_in[14];

    // workspace layout
    unsigned short* fw1t = (unsigned short*)d_ws;                       // 40960 B
    unsigned short* fw2t = (unsigned short*)((char*)d_ws + 40960);      //  8192 B
    float* h    = (float*)((char*)d_ws + 49152);                        // 12,800,000 B
    int*   deg  = (int*)((char*)d_ws + 12849152);                       //    200,000 B
    int*   curs = (int*)((char*)d_ws + 13049152);                       //    200,000 B
    int*   perm = (int*)((char*)d_ws + 13249152);                       //  3,200,000 B  (total ~16.5 MB)
    float* agg = (float*)d_out;

    hipMemsetAsync(d_out, 0, (size_t)out_size * sizeof(float), stream);
    hipMemsetAsync(deg, 0, (size_t)NNODES * sizeof(int), stream);
    prep_weights<<<64, 256, 0, stream>>>(fw1, fw2, fw1t, fw2t);
    linear1_kernel<<<(NNODES + 63) / 64, 256, 0, stream>>>(node_feature, l1w, l1b, h);
    hist_kernel<<<NEDGES / 256, 256, 0, stream>>>(ei, deg);
    scan_kernel<<<1, 1024, 0, stream>>>(deg, curs);
    scatter_kernel<<<NEDGES / 256, 256, 0, stream>>>(ei, curs, perm);
    edge_kernel<<<NEDGES / 64, 256, 0, stream>>>(ei, perm, rbf, dist, cutoff,
                                                 fw1t, fb1, fw2t, fb2, h, agg);
    output_kernel<<<(NNODES + 63) / 64, 256, 0, stream>>>(agg, node_feature, l2w, l2b, l3w, l3b);
}